// Round 13
// baseline (561.625 us; speedup 1.0000x reference)
//
#include <hip/hip_runtime.h>
#include <math.h>

typedef _Float16 hlf4 __attribute__((ext_vector_type(4)));
typedef _Float16 hlf8 __attribute__((ext_vector_type(8)));
typedef float f32x4 __attribute__((ext_vector_type(4)));

static __device__ __forceinline__ void gl_lds16(const void* g, void* l) {
    __builtin_amdgcn_global_load_lds(
        (const __attribute__((address_space(1))) unsigned int*)g,
        (__attribute__((address_space(3))) unsigned int*)l, 16, 0, 0);
}

// ---------------- block reductions (deterministic tree order) ----------------
static __device__ __forceinline__ float blk_sum(float v) {
    __shared__ float sm[256];
    int tid = threadIdx.x;
    sm[tid] = v; __syncthreads();
#pragma unroll
    for (int s = 128; s > 0; s >>= 1) {
        if (tid < s) sm[tid] += sm[tid + s];
        __syncthreads();
    }
    float r = sm[0]; __syncthreads();
    return r;
}

__global__ __launch_bounds__(256) void k_cinv(
    const float* __restrict__ norms, int m, int n, float* __restrict__ cinv) {
    float s = 0.f;
    for (int i = threadIdx.x; i < m; i += 256) s += norms[i];
    float tot = blk_sum(s);
    if (threadIdx.x == 0) cinv[0] = (float)m * sqrtf((float)n) / tot;  // 1/C
}

// ------- xs = x * (1/C) f32 (output) + UNSCALED f16 copy (LN-invariant) -----
__global__ __launch_bounds__(256) void k_scale2(
    const float* __restrict__ x, const float* __restrict__ cinv,
    float* __restrict__ y, _Float16* __restrict__ yh, long long total4) {
    float c = cinv[0];
    long long i = blockIdx.x * 256ll + threadIdx.x;
    long long stride = (long long)gridDim.x * 256ll;
    for (; i < total4; i += stride) {
        float4 v = ((const float4*)x)[i];
        float4 w = {v.x * c, v.y * c, v.z * c, v.w * c};
        ((float4*)y)[i] = w;
        hlf4 o = {(_Float16)v.x, (_Float16)v.y, (_Float16)v.z, (_Float16)v.w};
        ((hlf4*)yh)[i] = o;
    }
}

// ---- gather + cvt + fused row-norm (row already in registers) ----
__global__ __launch_bounds__(256) void k_gather_cvt(
    const float* __restrict__ X, const int* __restrict__ idx,
    _Float16* __restrict__ out, float* __restrict__ norms, int n) {
    long long r = idx[blockIdx.x];
    const float* src = X + r * (long long)n;
    _Float16* dst = out + (long long)blockIdx.x * n;
    float s = 0.f;
    for (int k = threadIdx.x * 4; k < n; k += 256 * 4) {
        float4 v = *(const float4*)(src + k);
        hlf4 o = {(_Float16)v.x, (_Float16)v.y, (_Float16)v.z, (_Float16)v.w};
        *(hlf4*)(dst + k) = o;
        s = fmaf(v.x, v.x, s); s = fmaf(v.y, v.y, s);
        s = fmaf(v.z, v.z, s); s = fmaf(v.w, v.w, s);
    }
    float tot = blk_sum(s);
    if (threadIdx.x == 0) norms[blockIdx.x] = sqrtf(tot);
}

// ---------------- flat f32 -> f16 with scalar scale ----------------
__global__ __launch_bounds__(256) void k_cvt(
    const float* __restrict__ in, _Float16* __restrict__ out, long long n4,
    float sc) {
    long long i = blockIdx.x * 256ll + threadIdx.x;
    long long stride = (long long)gridDim.x * 256ll;
    for (; i < n4; i += stride) {
        float4 v = ((const float4*)in)[i];
        hlf4 o = {(_Float16)(v.x * sc), (_Float16)(v.y * sc),
                  (_Float16)(v.z * sc), (_Float16)(v.w * sc)};
        ((hlf4*)out)[i] = o;
    }
}

// ---------------- transpose + cvt: in[R][Cc] f32 -> out[Cc][R] f16 ----------
__global__ __launch_bounds__(256) void k_tcvt(
    const float* __restrict__ in, _Float16* __restrict__ out, int R, int Cc) {
    __shared__ _Float16 t[32][34];
    int tx = threadIdx.x & 31, ty = threadIdx.x >> 5;
    int c0 = blockIdx.x * 32, r0 = blockIdx.y * 32;
#pragma unroll
    for (int i = 0; i < 32; i += 8)
        t[ty + i][tx] = (_Float16)in[(long long)(r0 + ty + i) * Cc + c0 + tx];
    __syncthreads();
#pragma unroll
    for (int i = 0; i < 32; i += 8)
        out[(long long)(c0 + ty + i) * R + r0 + tx] = t[tx][ty + i];
}

// ================= m97-structure MFMA NT GEMM (128² tile, 4 waves) ==========
// Proven kernel for the small q/k projections.
__global__ __launch_bounds__(256) void k_gemm4(
    const _Float16* __restrict__ A, int lda,
    const _Float16* __restrict__ B, int ldb,
    float* __restrict__ Cc, long long ldc, int K) {
    __shared__ _Float16 Ah[2][4096];
    __shared__ _Float16 Bh[2][4096];
    const int tid = threadIdx.x;
    const int gx = gridDim.x, gy = gridDim.y;
    int lin = blockIdx.x + gx * blockIdx.y;
    const int cpx = (gx * gy) >> 3;
    lin = (lin & 7) * cpx + (lin >> 3);
    const int by = lin % gy;
    const int bx = lin / gy;
    const long long m0 = (long long)bx * 128;
    const long long n0 = (long long)by * 128;
    const int lane = tid & 63, wv = tid >> 6;
    const int wm = (wv >> 1) * 64, wn = (wv & 1) * 64;
    const int fr = lane & 15, fq = lane >> 4;

    const int s0 = tid, s1 = tid + 256;
    const int r0s = s0 >> 2, r1s = s1 >> 2;
    const int g0 = (((s0 & 3) ^ (r0s & 3)) << 3);
    const int g1 = (((s1 & 3) ^ (r1s & 3)) << 3);
    const _Float16* A0 = A + (m0 + r0s) * (long long)lda + g0;
    const _Float16* A1 = A + (m0 + r1s) * (long long)lda + g1;
    const _Float16* B0 = B + (n0 + r0s) * (long long)ldb + g0;
    const _Float16* B1 = B + (n0 + r1s) * (long long)ldb + g1;

    f32x4 acc[4][4] = {};

    const int NT = K / 32;
    {
        gl_lds16(A0, &Ah[0][wv * 512]);
        gl_lds16(A1, &Ah[0][2048 + wv * 512]);
        gl_lds16(B0, &Bh[0][wv * 512]);
        gl_lds16(B1, &Bh[0][2048 + wv * 512]);
    }
    __syncthreads();

    for (int kt = 0; kt < NT; ++kt) {
        const int cur = kt & 1;
        if (kt + 1 < NT) {
            const int nx = cur ^ 1;
            const long long ko = (long long)(kt + 1) * 32;
            gl_lds16(A0 + ko, &Ah[nx][wv * 512]);
            gl_lds16(A1 + ko, &Ah[nx][2048 + wv * 512]);
            gl_lds16(B0 + ko, &Bh[nx][wv * 512]);
            gl_lds16(B1 + ko, &Bh[nx][2048 + wv * 512]);
        }
        hlf8 af[4], bf[4];
#pragma unroll
        for (int i = 0; i < 4; ++i) {
            const int r = wm + i * 16 + fr;
            af[i] = *(const hlf8*)&Ah[cur][r * 32 + ((fq ^ (r & 3)) << 3)];
        }
#pragma unroll
        for (int j = 0; j < 4; ++j) {
            const int r = wn + j * 16 + fr;
            bf[j] = *(const hlf8*)&Bh[cur][r * 32 + ((fq ^ (r & 3)) << 3)];
        }
#pragma unroll
        for (int i = 0; i < 4; ++i)
#pragma unroll
            for (int j = 0; j < 4; ++j)
                acc[i][j] = __builtin_amdgcn_mfma_f32_16x16x32_f16(af[i], bf[j], acc[i][j], 0, 0, 0);
        __syncthreads();
    }

#pragma unroll
    for (int i = 0; i < 4; ++i)
#pragma unroll
        for (int j = 0; j < 4; ++j) {
            float* cp = Cc + (m0 + wm + i * 16 + fq * 4) * ldc + (n0 + wn + j * 16 + fr);
#pragma unroll
            for (int r = 0; r < 4; ++r) cp[(long long)r * ldc] = acc[i][j][r];
        }
}

// ========== 256² 8-phase NT GEMM — derived staging schedule =================
// C = A·B^T. BM=BN=256, BK=64, 512 thr / 8 waves (2Mx4N, 128x64/wave).
// LDS 128 KiB: Ah/Bh[2][256][64] f16 (dbuf). Per tile τ, 4 quadrant phases
// (R7-verified reads/MFMA); staging = ONE half-tile (2 gl_lds/thread)/phase:
//   P1: stage B1(τ+1)   [opp buf; tenant τ-1 done]   reads a0(8)+b0(4), MFMA q00
//   P2: stage A1(τ+1)   [opp buf]                    reads b1(4),       MFMA q01
//   P3: stage B0(τ+2)   [this buf; B-h0 free: read only P1,P2]  a1(8),  MFMA q10
//   P4: stage A0(τ+2)   [this buf; A free: read P1,P3]          -,      MFMA q11
// Tile boundary: s_waitcnt vmcnt(4) (newest 2 stage-events = B0/A0(τ+2) may
// fly; tile τ+1's halves proven landed) — never 0 mid-loop (T4). Prologue
// stages B0,A0,B1,A1(0),B0,A0(1) so the first boundary is steady-state.
// Swizzle as R6/R7 (verified 0-conflict): 16B slot p holds k-group p^(row&7),
// applied to global source AND frag reads. MODE: 0=f32 C / split-K partial;
// 1=f16 exp(C-5) epilogue.
template <int MODE>
__global__ __launch_bounds__(512) void k256(
    const _Float16* __restrict__ A, int lda,
    const _Float16* __restrict__ B, int ldb,
    void* __restrict__ Cc, long long ldc, int K,
    float* __restrict__ part, long long zstride) {
    __shared__ _Float16 Ah[2][16384];
    __shared__ _Float16 Bh[2][16384];
    const int tid = threadIdx.x, lane = tid & 63, wv = tid >> 6;

    const int gx = gridDim.x, gy = gridDim.y;
    int lin = blockIdx.x + gx * (blockIdx.y + gy * blockIdx.z);
    const int cpx = (gx * gy * (int)gridDim.z) >> 3;
    lin = (lin & 7) * cpx + (lin >> 3);
    const int by = lin % gy;
    const int rest = lin / gy;
    const int bx = rest % gx, bz = rest / gx;

    const long long m0 = (long long)bx * 256;
    const long long n0 = (long long)by * 256;
    const int KC = K / gridDim.z;
    const int kbase = bz * KC;
    const int wm = (wv >> 2) * 128, wn = (wv & 3) * 64;
    const int fr = lane & 15, fq = lane >> 4;

    // staging slots within a half (1024 16B-slots): this thread covers
    // s=tid and s=tid+512. slot s: row_in_half=s>>3, kgroup=((s&7)^(row&7))<<3.
    const int sa = tid, sb = tid + 512;
    const int ra = sa >> 3, ga = (((sa & 7) ^ (ra & 7)) << 3);
    const int rb = sb >> 3, gb = (((sb & 7) ^ (rb & 7)) << 3);
    const _Float16* As0 = A + (m0 + ra) * (long long)lda + kbase + ga;
    const _Float16* As1 = A + (m0 + rb) * (long long)lda + kbase + gb;
    const _Float16* Bs0 = B + (n0 + ra) * (long long)ldb + kbase + ga;
    const _Float16* Bs1 = B + (n0 + rb) * (long long)ldb + kbase + gb;

    f32x4 acc[8][4] = {};
    const int NT = KC / 64;   // NT >= 2 for all launches here

    // stage half h of tile kt of matrix (s0/s1 src, ld) into larr[bufi]
#define STG(s0p, s1p, ldm, larr, bufi, h, kt)                                  \
    {                                                                          \
        const long long o_ = (long long)(kt) * 64 + (long long)(h) * 128 * (ldm); \
        gl_lds16((s0p) + o_, &larr[bufi][((h) * 1024 + wv * 64) * 8]);         \
        gl_lds16((s1p) + o_, &larr[bufi][((h) * 1024 + 512 + wv * 64) * 8]);   \
    }

    // prologue: B0(0),A0(0),B1(0),A1(0),B0(1),A0(1)
    STG(Bs0, Bs1, ldb, Bh, 0, 0, 0);
    STG(As0, As1, lda, Ah, 0, 0, 0);
    STG(Bs0, Bs1, ldb, Bh, 0, 1, 0);
    STG(As0, As1, lda, Ah, 0, 1, 0);
    STG(Bs0, Bs1, ldb, Bh, 1, 0, 1);
    STG(As0, As1, lda, Ah, 1, 0, 1);

    for (int kt = 0; kt < NT; ++kt) {
        const int cur = kt & 1;
        if (kt + 1 < NT) asm volatile("s_waitcnt vmcnt(4)" ::: "memory");
        else             asm volatile("s_waitcnt vmcnt(0)" ::: "memory");
        __builtin_amdgcn_s_barrier();

        hlf8 a0[4][2], a1[4][2], b0[2][2], b1[2][2];
        // ---------------- P1: stage B1(kt+1); read a0+b0; MFMA q00 ----------
        if (kt + 1 < NT) STG(Bs0, Bs1, ldb, Bh, cur ^ 1, 1, kt + 1);
#pragma unroll
        for (int i = 0; i < 4; ++i)
#pragma unroll
            for (int ks = 0; ks < 2; ++ks) {
                const int rr = wm + i * 16 + fr;
                a0[i][ks] = *(const hlf8*)&Ah[cur][rr * 64 + (((ks * 4 + fq) ^ (rr & 7)) << 3)];
            }
#pragma unroll
        for (int jj = 0; jj < 2; ++jj)
#pragma unroll
            for (int ks = 0; ks < 2; ++ks) {
                const int cc = wn + jj * 16 + fr;
                b0[jj][ks] = *(const hlf8*)&Bh[cur][cc * 64 + (((ks * 4 + fq) ^ (cc & 7)) << 3)];
            }
        __builtin_amdgcn_s_barrier();
        asm volatile("s_waitcnt lgkmcnt(0)" ::: "memory");
        __builtin_amdgcn_sched_barrier(0);
        __builtin_amdgcn_s_setprio(1);
#pragma unroll
        for (int i = 0; i < 4; ++i)
#pragma unroll
            for (int jj = 0; jj < 2; ++jj)
#pragma unroll
                for (int ks = 0; ks < 2; ++ks)
                    acc[i][jj] = __builtin_amdgcn_mfma_f32_16x16x32_f16(a0[i][ks], b0[jj][ks], acc[i][jj], 0, 0, 0);
        __builtin_amdgcn_s_setprio(0);
        __builtin_amdgcn_s_barrier();

        // ---------------- P2: stage A1(kt+1); read b1; MFMA q01 -------------
        if (kt + 1 < NT) STG(As0, As1, lda, Ah, cur ^ 1, 1, kt + 1);
#pragma unroll
        for (int jj = 0; jj < 2; ++jj)
#pragma unroll
            for (int ks = 0; ks < 2; ++ks) {
                const int cc = wn + (jj + 2) * 16 + fr;
                b1[jj][ks] = *(const hlf8*)&Bh[cur][cc * 64 + (((ks * 4 + fq) ^ (cc & 7)) << 3)];
            }
        __builtin_amdgcn_s_barrier();
        asm volatile("s_waitcnt lgkmcnt(0)" ::: "memory");
        __builtin_amdgcn_sched_barrier(0);
        __builtin_amdgcn_s_setprio(1);
#pragma unroll
        for (int i = 0; i < 4; ++i)
#pragma unroll
            for (int jj = 0; jj < 2; ++jj)
#pragma unroll
                for (int ks = 0; ks < 2; ++ks)
                    acc[i][jj + 2] = __builtin_amdgcn_mfma_f32_16x16x32_f16(a0[i][ks], b1[jj][ks], acc[i][jj + 2], 0, 0, 0);
        __builtin_amdgcn_s_setprio(0);
        __builtin_amdgcn_s_barrier();

        // ---------------- P3: stage B0(kt+2); read a1; MFMA q10 -------------
        if (kt + 2 < NT) STG(Bs0, Bs1, ldb, Bh, cur, 0, kt + 2);
#pragma unroll
        for (int i = 0; i < 4; ++i)
#pragma unroll
            for (int ks = 0; ks < 2; ++ks) {
                const int rr = wm + (i + 4) * 16 + fr;
                a1[i][ks] = *(const hlf8*)&Ah[cur][rr * 64 + (((ks * 4 + fq) ^ (rr & 7)) << 3)];
            }
        __builtin_amdgcn_s_barrier();
        asm volatile("s_waitcnt lgkmcnt(0)" ::: "memory");
        __builtin_amdgcn_sched_barrier(0);
        __builtin_amdgcn_s_setprio(1);
#pragma unroll
        for (int i = 0; i < 4; ++i)
#pragma unroll
            for (int jj = 0; jj < 2; ++jj)
#pragma unroll
                for (int ks = 0; ks < 2; ++ks)
                    acc[i + 4][jj] = __builtin_amdgcn_mfma_f32_16x16x32_f16(a1[i][ks], b0[jj][ks], acc[i + 4][jj], 0, 0, 0);
        __builtin_amdgcn_s_setprio(0);
        __builtin_amdgcn_s_barrier();

        // ---------------- P4: stage A0(kt+2); MFMA q11 (regs only) ----------
        if (kt + 2 < NT) STG(As0, As1, lda, Ah, cur, 0, kt + 2);
        __builtin_amdgcn_s_setprio(1);
#pragma unroll
        for (int i = 0; i < 4; ++i)
#pragma unroll
            for (int jj = 0; jj < 2; ++jj)
#pragma unroll
                for (int ks = 0; ks < 2; ++ks)
                    acc[i + 4][jj + 2] = __builtin_amdgcn_mfma_f32_16x16x32_f16(a1[i][ks], b1[jj][ks], acc[i + 4][jj + 2], 0, 0, 0);
        __builtin_amdgcn_s_setprio(0);
        // boundary wait+barrier at next iteration top closes the tile
    }
#undef STG

    // C/D layout: col=lane&15, row=(lane>>4)*4+reg (m89-verified)
    if constexpr (MODE == 1) {
        _Float16* op = (_Float16*)Cc;
#pragma unroll
        for (int i = 0; i < 8; ++i)
#pragma unroll
            for (int j = 0; j < 4; ++j) {
                _Float16* cp = op + (m0 + wm + i * 16 + fq * 4) * ldc + (n0 + wn + j * 16 + fr);
#pragma unroll
                for (int r = 0; r < 4; ++r)
                    cp[(long long)r * ldc] = (_Float16)__expf(acc[i][j][r] - 5.0f);
            }
    } else {
        float* outp = (gridDim.z == 1) ? (float*)Cc : (part + (long long)bz * zstride);
#pragma unroll
        for (int i = 0; i < 8; ++i)
#pragma unroll
            for (int j = 0; j < 4; ++j) {
                float* cp = outp + (m0 + wm + i * 16 + fq * 4) * ldc + (n0 + wn + j * 16 + fr);
#pragma unroll
                for (int r = 0; r < 4; ++r) cp[(long long)r * ldc] = acc[i][j][r];
            }
    }
}

// ------- split-K reduction with optional per-row scale: out = inv[row]*Σ ----
__global__ __launch_bounds__(256) void k_redux(
    const float* __restrict__ part, float* __restrict__ out,
    long long n4, long long zs4, int Z,
    const float* __restrict__ invs, int rowdiv4) {
    long long i = blockIdx.x * 256ll + threadIdx.x;
    long long stride = (long long)gridDim.x * 256ll;
    for (; i < n4; i += stride) {
        float4 s = ((const float4*)part)[i];
        for (int z = 1; z < Z; ++z) {
            float4 t = ((const float4*)part)[i + z * zs4];
            s.x += t.x; s.y += t.y; s.z += t.z; s.w += t.w;
        }
        if (invs) {
            float iv = invs[i / rowdiv4];
            s.x *= iv; s.y *= iv; s.z *= iv; s.w *= iv;
        }
        ((float4*)out)[i] = s;
    }
}

// ---------------- row LayerNorm in-place (f32), width W = CNT*256 -----------
template <int CNT>
__global__ __launch_bounds__(256) void k_layernorm(
    float* __restrict__ Y, const float* __restrict__ g,
    const float* __restrict__ b, int W) {
    float* yr = Y + (long long)blockIdx.x * W;
    float v[CNT];
    float s = 0.f;
#pragma unroll
    for (int i = 0; i < CNT; ++i) {
        v[i] = yr[threadIdx.x + (i << 8)];
        s += v[i];
    }
    float mu = blk_sum(s) / (float)W;
    float sq = 0.f;
#pragma unroll
    for (int i = 0; i < CNT; ++i) {
        float d = v[i] - mu;
        sq = fmaf(d, d, sq);
    }
    float var = blk_sum(sq) / (float)W;
    float rs = rsqrtf(var + 1e-5f);
#pragma unroll
    for (int i = 0; i < CNT; ++i) {
        int col = threadIdx.x + (i << 8);
        yr[col] = (v[i] - mu) * rs * g[col] + b[col];
    }
}

// ---- row LayerNorm f32 -> f16 (scaled); for q,k whose f32 isn't an output --
__global__ __launch_bounds__(256) void k_layernorm_h(
    const float* __restrict__ Y, const float* __restrict__ g,
    const float* __restrict__ b, _Float16* __restrict__ outh, int W, float sc) {
    const float* yr = Y + (long long)blockIdx.x * W;
    _Float16* orow = outh + (long long)blockIdx.x * W;
    float v = yr[threadIdx.x];                       // W == 256 here
    float mu = blk_sum(v) / (float)W;
    float d = v - mu;
    float var = blk_sum(d * d) / (float)W;
    float rs = rsqrtf(var + 1e-5f);
    orow[threadIdx.x] = (_Float16)((d * rs * g[threadIdx.x] + b[threadIdx.x]) * sc);
}

// -------- sum-only softmax over E = exp(S-5) f16, W = 16384 -----------------
__global__ __launch_bounds__(256) void k_softmax_e(
    const _Float16* __restrict__ E, float* __restrict__ attnf,
    float* __restrict__ invs) {
    const _Float16* er = E + (long long)blockIdx.x * 16384;
    float* ar = attnf + (long long)blockIdx.x * 16384;
    float4 r[16];
    float sum = 0.f;
#pragma unroll
    for (int i = 0; i < 16; ++i) {
        hlf4 h = ((const hlf4*)er)[threadIdx.x + (i << 8)];
        float4 t = {(float)h[0], (float)h[1], (float)h[2], (float)h[3]};
        r[i] = t;
        sum += t.x + t.y + t.z + t.w;
    }
    sum = blk_sum(sum);
    float inv = 1.0f / sum;
    if (threadIdx.x == 0) invs[blockIdx.x] = inv;
#pragma unroll
    for (int i = 0; i < 16; ++i) {
        float4 t = r[i];
        t.x *= inv; t.y *= inv; t.z *= inv; t.w *= inv;
        ((float4*)ar)[threadIdx.x + (i << 8)] = t;
    }
}

extern "C" void kernel_launch(void* const* d_in, const int* in_sizes, int n_in,
                              void* d_out, int out_size, void* d_ws, size_t ws_size,
                              hipStream_t stream) {
    const float* x      = (const float*)d_in[0];
    const float* X_data = (const float*)d_in[1];
    const int*   midx   = (const int*)d_in[2];
    const float* W_q    = (const float*)d_in[3];
    const float* W_k    = (const float*)d_in[4];
    const float* W_v    = (const float*)d_in[5];
    const float* g_q    = (const float*)d_in[6];
    const float* b_q    = (const float*)d_in[7];
    const float* g_k    = (const float*)d_in[8];
    const float* b_k    = (const float*)d_in[9];
    const float* g_v    = (const float*)d_in[10];
    const float* b_v    = (const float*)d_in[11];

    const int n  = in_sizes[10];        // 1024
    const int a  = in_sizes[6];         // 256
    const int m  = in_sizes[2];         // 16384
    const int Bn = in_sizes[0] / n;     // 4096

    // output layout: xs | x_hat | attn | v
    float* out  = (float*)d_out;
    float* xs   = out;
    float* xhat = xs + (long long)Bn * n;
    float* attn = xhat + (long long)Bn * n;
    float* vout = attn + (long long)Bn * m;

    char* wp = (char*)d_ws;
    auto carve = [&](size_t bytes) -> char* {
        char* r = wp; wp += (bytes + 255) & ~(size_t)255; return r;
    };
    float*     norms = (float*)carve((size_t)m * 4);
    float*     cinv  = (float*)carve(16);
    float*     invs  = (float*)carve((size_t)Bn * 4);
    char*      alias0 = wp;
    float*     qmat  = (float*)carve((size_t)Bn * a * 4);
    float*     kmat  = (float*)carve((size_t)m * a * 4);
    _Float16*  xs_h  = (_Float16*)carve((size_t)Bn * n * 2);
    _Float16*  Xc_h  = (_Float16*)carve((size_t)m * n * 2);
    _Float16*  Wq_h  = (_Float16*)carve((size_t)a * n * 2);
    _Float16*  Wk_h  = (_Float16*)carve((size_t)a * n * 2);
    _Float16*  Wv_h  = (_Float16*)carve((size_t)n * n * 2);
    _Float16*  q_h   = (_Float16*)carve((size_t)Bn * a * 2);
    _Float16*  k_h   = (_Float16*)carve((size_t)m * a * 2);
    float*     splitk = (float*)alias0;
    const int  SK = 4;                                    // SK*Bn*n*4 = 64MB <= 73MB
    _Float16*  vT_h  = (_Float16*)carve((size_t)n * m * 2);
    size_t used = (size_t)(wp - (char*)d_ws);
    _Float16* attn_h = nullptr;
    if (ws_size >= used + (size_t)Bn * m * 2 + 256)
        attn_h = (_Float16*)carve((size_t)Bn * m * 2);

    // 1) gather + cvt + fused row norms; then 1/C
    hipLaunchKernelGGL(k_gather_cvt, dim3(m), dim3(256), 0, stream,
                       X_data, midx, Xc_h, norms, n);
    hipLaunchKernelGGL(k_cinv, dim3(1), dim3(256), 0, stream, norms, m, n, cinv);

    // 2) xs = x/C (f32 output) + unscaled f16 copy for q projection
    hipLaunchKernelGGL(k_scale2, dim3(2048), dim3(256), 0, stream,
                       x, cinv, xs, xs_h, (long long)Bn * n / 4);

    // 3) weights -> f16
    hipLaunchKernelGGL(k_cvt, dim3(256), dim3(256), 0, stream, W_q, Wq_h, (long long)a * n / 4, 1.f);
    hipLaunchKernelGGL(k_cvt, dim3(256), dim3(256), 0, stream, W_k, Wk_h, (long long)a * n / 4, 1.f);
    hipLaunchKernelGGL(k_cvt, dim3(1024), dim3(256), 0, stream, W_v, Wv_h, (long long)n * n / 4, 1.f);

    // 4) projections: q,k on 128²; v on the 8-phase 256² kernel
    hipLaunchKernelGGL(k_gemm4, dim3(Bn / 128, a / 128), dim3(256), 0, stream,
                       xs_h, n, Wq_h, n, qmat, a, n);
    hipLaunchKernelGGL(k_gemm4, dim3(m / 128, a / 128), dim3(256), 0, stream,
                       Xc_h, n, Wk_h, n, kmat, a, n);
    hipLaunchKernelGGL((k256<0>), dim3(m / 256, n / 256), dim3(512), 0, stream,
                       Xc_h, n, Wv_h, n, vout, n, n, (float*)nullptr, 0ll);

    // 5) LayerNorms: q,k fused f32->f16 (scale folded); v f32 + transposed f16
    float sc = 1.0f / sqrtf((float)a);
    hipLaunchKernelGGL(k_layernorm_h, dim3(Bn), dim3(256), 0, stream,
                       qmat, g_q, b_q, q_h, a, sc);
    hipLaunchKernelGGL(k_layernorm_h, dim3(m), dim3(256), 0, stream,
                       kmat, g_k, b_k, k_h, a, 1.f);
    hipLaunchKernelGGL(k_layernorm<4>, dim3(m), dim3(256), 0, stream, vout, g_v, b_v, n);
    hipLaunchKernelGGL(k_tcvt, dim3(n / 32, m / 32), dim3(256), 0, stream, vout, vT_h, m, n);

    long long zstride = (long long)Bn * n;
    if (attn_h) {
        // 6) E = exp(q·kᵀ·sc − 5) f16 in 256²-GEMM epilogue; sum-only softmax
        hipLaunchKernelGGL((k256<1>), dim3(Bn / 256, m / 256), dim3(512), 0, stream,
                           q_h, a, k_h, a, attn_h, m, a, (float*)nullptr, 0ll);
        hipLaunchKernelGGL(k_softmax_e, dim3(Bn), dim3(256), 0, stream,
                           attn_h, attn, invs);
        // 7) x_hat = (E @ v) * inv_sum[row], split-K=4 + scaled reduce
        hipLaunchKernelGGL((k256<0>), dim3(Bn / 256, n / 256, SK), dim3(512), 0, stream,
                           attn_h, m, vT_h, m, xhat, n, m, splitk, zstride);
        hipLaunchKernelGGL(k_redux, dim3(2048), dim3(256), 0, stream,
                           splitk, xhat, (long long)Bn * n / 4, zstride / 4, SK,
                           invs, n / 4);
    } else {
        // fallback (never exercised): chunked E in splitk region
        _Float16* chunk_h = (_Float16*)splitk;           // 1024*16384*2 = 32MB
        for (int cb = 0; cb < 4; ++cb) {
            hipLaunchKernelGGL((k256<1>), dim3(1024 / 256, m / 256), dim3(512), 0, stream,
                               q_h + (long long)cb * 1024 * a, a, k_h, a,
                               chunk_h, m, a, (float*)nullptr, 0ll);
            hipLaunchKernelGGL(k_softmax_e, dim3(1024), dim3(256), 0, stream,
                               chunk_h, attn + (long long)cb * 1024 * m,
                               invs + (long long)cb * 1024);
            hipLaunchKernelGGL((k256<0>), dim3(1024 / 256, n / 256), dim3(512), 0, stream,
                               chunk_h, m, vT_h, m, xhat + (long long)cb * 1024 * n, n, m,
                               (float*)nullptr, 0ll);
        }
        hipLaunchKernelGGL(k_redux, dim3(2048), dim3(256), 0, stream,
                           xhat, xhat, (long long)Bn * n / 4, 0ll, 1, invs, n / 4);
    }
}

// Round 14
// 559.784 us; speedup vs baseline: 1.0033x; 1.0033x over previous
//
#include <hip/hip_runtime.h>
#include <math.h>

typedef _Float16 hlf4 __attribute__((ext_vector_type(4)));
typedef _Float16 hlf8 __attribute__((ext_vector_type(8)));
typedef float f32x4 __attribute__((ext_vector_type(4)));

static __device__ __forceinline__ void gl_lds16(const void* g, void* l) {
    __builtin_amdgcn_global_load_lds(
        (const __attribute__((address_space(1))) unsigned int*)g,
        (__attribute__((address_space(3))) unsigned int*)l, 16, 0, 0);
}

// raw s_barrier WITH compiler memory fence (no vmcnt/lgkm drain)
#define SBAR() asm volatile("s_barrier" ::: "memory")

// ---------------- block reductions (deterministic tree order) ----------------
static __device__ __forceinline__ float blk_sum(float v) {
    __shared__ float sm[256];
    int tid = threadIdx.x;
    sm[tid] = v; __syncthreads();
#pragma unroll
    for (int s = 128; s > 0; s >>= 1) {
        if (tid < s) sm[tid] += sm[tid + s];
        __syncthreads();
    }
    float r = sm[0]; __syncthreads();
    return r;
}

__global__ __launch_bounds__(256) void k_cinv(
    const float* __restrict__ norms, int m, int n, float* __restrict__ cinv) {
    float s = 0.f;
    for (int i = threadIdx.x; i < m; i += 256) s += norms[i];
    float tot = blk_sum(s);
    if (threadIdx.x == 0) cinv[0] = (float)m * sqrtf((float)n) / tot;  // 1/C
}

// ------- xs = x * (1/C) f32 (output) + UNSCALED f16 copy (LN-invariant) -----
__global__ __launch_bounds__(256) void k_scale2(
    const float* __restrict__ x, const float* __restrict__ cinv,
    float* __restrict__ y, _Float16* __restrict__ yh, long long total4) {
    float c = cinv[0];
    long long i = blockIdx.x * 256ll + threadIdx.x;
    long long stride = (long long)gridDim.x * 256ll;
    for (; i < total4; i += stride) {
        float4 v = ((const float4*)x)[i];
        float4 w = {v.x * c, v.y * c, v.z * c, v.w * c};
        ((float4*)y)[i] = w;
        hlf4 o = {(_Float16)v.x, (_Float16)v.y, (_Float16)v.z, (_Float16)v.w};
        ((hlf4*)yh)[i] = o;
    }
}

// ---- gather + cvt + fused row-norm (row already in registers) ----
__global__ __launch_bounds__(256) void k_gather_cvt(
    const float* __restrict__ X, const int* __restrict__ idx,
    _Float16* __restrict__ out, float* __restrict__ norms, int n) {
    long long r = idx[blockIdx.x];
    const float* src = X + r * (long long)n;
    _Float16* dst = out + (long long)blockIdx.x * n;
    float s = 0.f;
    for (int k = threadIdx.x * 4; k < n; k += 256 * 4) {
        float4 v = *(const float4*)(src + k);
        hlf4 o = {(_Float16)v.x, (_Float16)v.y, (_Float16)v.z, (_Float16)v.w};
        *(hlf4*)(dst + k) = o;
        s = fmaf(v.x, v.x, s); s = fmaf(v.y, v.y, s);
        s = fmaf(v.z, v.z, s); s = fmaf(v.w, v.w, s);
    }
    float tot = blk_sum(s);
    if (threadIdx.x == 0) norms[blockIdx.x] = sqrtf(tot);
}

// ---------------- flat f32 -> f16 with scalar scale ----------------
__global__ __launch_bounds__(256) void k_cvt(
    const float* __restrict__ in, _Float16* __restrict__ out, long long n4,
    float sc) {
    long long i = blockIdx.x * 256ll + threadIdx.x;
    long long stride = (long long)gridDim.x * 256ll;
    for (; i < n4; i += stride) {
        float4 v = ((const float4*)in)[i];
        hlf4 o = {(_Float16)(v.x * sc), (_Float16)(v.y * sc),
                  (_Float16)(v.z * sc), (_Float16)(v.w * sc)};
        ((hlf4*)out)[i] = o;
    }
}

// ---------------- transpose + cvt: in[R][Cc] f32 -> out[Cc][R] f16 ----------
__global__ __launch_bounds__(256) void k_tcvt(
    const float* __restrict__ in, _Float16* __restrict__ out, int R, int Cc) {
    __shared__ _Float16 t[32][34];
    int tx = threadIdx.x & 31, ty = threadIdx.x >> 5;
    int c0 = blockIdx.x * 32, r0 = blockIdx.y * 32;
#pragma unroll
    for (int i = 0; i < 32; i += 8)
        t[ty + i][tx] = (_Float16)in[(long long)(r0 + ty + i) * Cc + c0 + tx];
    __syncthreads();
#pragma unroll
    for (int i = 0; i < 32; i += 8)
        out[(long long)(c0 + ty + i) * R + r0 + tx] = t[tx][ty + i];
}

// ================= m97-structure MFMA NT GEMM (128² tile, 4 waves) ==========
__global__ __launch_bounds__(256) void k_gemm4(
    const _Float16* __restrict__ A, int lda,
    const _Float16* __restrict__ B, int ldb,
    float* __restrict__ Cc, long long ldc, int K) {
    __shared__ _Float16 Ah[2][4096];
    __shared__ _Float16 Bh[2][4096];
    const int tid = threadIdx.x;
    const int gx = gridDim.x, gy = gridDim.y;
    int lin = blockIdx.x + gx * blockIdx.y;
    const int cpx = (gx * gy) >> 3;
    lin = (lin & 7) * cpx + (lin >> 3);
    const int by = lin % gy;
    const int bx = lin / gy;
    const long long m0 = (long long)bx * 128;
    const long long n0 = (long long)by * 128;
    const int lane = tid & 63, wv = tid >> 6;
    const int wm = (wv >> 1) * 64, wn = (wv & 1) * 64;
    const int fr = lane & 15, fq = lane >> 4;

    const int s0 = tid, s1 = tid + 256;
    const int r0s = s0 >> 2, r1s = s1 >> 2;
    const int g0 = (((s0 & 3) ^ (r0s & 3)) << 3);
    const int g1 = (((s1 & 3) ^ (r1s & 3)) << 3);
    const _Float16* A0 = A + (m0 + r0s) * (long long)lda + g0;
    const _Float16* A1 = A + (m0 + r1s) * (long long)lda + g1;
    const _Float16* B0 = B + (n0 + r0s) * (long long)ldb + g0;
    const _Float16* B1 = B + (n0 + r1s) * (long long)ldb + g1;

    f32x4 acc[4][4] = {};

    const int NT = K / 32;
    {
        gl_lds16(A0, &Ah[0][wv * 512]);
        gl_lds16(A1, &Ah[0][2048 + wv * 512]);
        gl_lds16(B0, &Bh[0][wv * 512]);
        gl_lds16(B1, &Bh[0][2048 + wv * 512]);
    }
    __syncthreads();

    for (int kt = 0; kt < NT; ++kt) {
        const int cur = kt & 1;
        if (kt + 1 < NT) {
            const int nx = cur ^ 1;
            const long long ko = (long long)(kt + 1) * 32;
            gl_lds16(A0 + ko, &Ah[nx][wv * 512]);
            gl_lds16(A1 + ko, &Ah[nx][2048 + wv * 512]);
            gl_lds16(B0 + ko, &Bh[nx][wv * 512]);
            gl_lds16(B1 + ko, &Bh[nx][2048 + wv * 512]);
        }
        hlf8 af[4], bf[4];
#pragma unroll
        for (int i = 0; i < 4; ++i) {
            const int r = wm + i * 16 + fr;
            af[i] = *(const hlf8*)&Ah[cur][r * 32 + ((fq ^ (r & 3)) << 3)];
        }
#pragma unroll
        for (int j = 0; j < 4; ++j) {
            const int r = wn + j * 16 + fr;
            bf[j] = *(const hlf8*)&Bh[cur][r * 32 + ((fq ^ (r & 3)) << 3)];
        }
#pragma unroll
        for (int i = 0; i < 4; ++i)
#pragma unroll
            for (int j = 0; j < 4; ++j)
                acc[i][j] = __builtin_amdgcn_mfma_f32_16x16x32_f16(af[i], bf[j], acc[i][j], 0, 0, 0);
        __syncthreads();
    }

#pragma unroll
    for (int i = 0; i < 4; ++i)
#pragma unroll
        for (int j = 0; j < 4; ++j) {
            float* cp = Cc + (m0 + wm + i * 16 + fq * 4) * ldc + (n0 + wn + j * 16 + fr);
#pragma unroll
            for (int r = 0; r < 4; ++r) cp[(long long)r * ldc] = acc[i][j][r];
        }
}

// ========== 256² 8-phase NT GEMM — R13 schedule, compiler-scheduled reads ===
// Identical staging/barrier/swizzle structure to R13 (passed) with ONE change:
// the per-phase `s_waitcnt lgkmcnt(0)` + `sched_barrier(0)` pins are REMOVED.
// MFMA ordering comes from C++ dataflow (compiler emits fine-grained
// lgkmcnt(N) so early MFMAs start as soon as their own operands land — m97
// asm evidence; m141 measured the pinned version as the regression).
// Race safety unchanged: a region's reads are lgkm-complete before the
// reader's phase-end barrier (forced by its own MFMA deps), and the staging
// write to that region issues only after that barrier.
template <int MODE>
__global__ __launch_bounds__(512) void k256(
    const _Float16* __restrict__ A, int lda,
    const _Float16* __restrict__ B, int ldb,
    void* __restrict__ Cc, long long ldc, int K,
    float* __restrict__ part, long long zstride) {
    __shared__ _Float16 Ah[2][16384];
    __shared__ _Float16 Bh[2][16384];
    const int tid = threadIdx.x, lane = tid & 63, wv = tid >> 6;

    const int gx = gridDim.x, gy = gridDim.y;
    int lin = blockIdx.x + gx * (blockIdx.y + gy * blockIdx.z);
    const int cpx = (gx * gy * (int)gridDim.z) >> 3;
    lin = (lin & 7) * cpx + (lin >> 3);
    const int by = lin % gy;
    const int rest = lin / gy;
    const int bx = rest % gx, bz = rest / gx;

    const long long m0 = (long long)bx * 256;
    const long long n0 = (long long)by * 256;
    const int KC = K / gridDim.z;
    const int kbase = bz * KC;
    const int wm = (wv >> 2) * 128, wn = (wv & 3) * 64;
    const int fr = lane & 15, fq = lane >> 4;

    const int sa = tid, sb = tid + 512;
    const int ra = sa >> 3, ga = (((sa & 7) ^ (ra & 7)) << 3);
    const int rb = sb >> 3, gb = (((sb & 7) ^ (rb & 7)) << 3);
    const _Float16* As0 = A + (m0 + ra) * (long long)lda + kbase + ga;
    const _Float16* As1 = A + (m0 + rb) * (long long)lda + kbase + gb;
    const _Float16* Bs0 = B + (n0 + ra) * (long long)ldb + kbase + ga;
    const _Float16* Bs1 = B + (n0 + rb) * (long long)ldb + kbase + gb;

    f32x4 acc[8][4] = {};
    const int NT = KC / 64;   // NT >= 2 for all launches here

#define STG(s0p, s1p, ldm, larr, bufi, h, kt)                                  \
    {                                                                          \
        const long long o_ = (long long)(kt) * 64 + (long long)(h) * 128 * (ldm); \
        gl_lds16((s0p) + o_, &larr[bufi][((h) * 1024 + wv * 64) * 8]);         \
        gl_lds16((s1p) + o_, &larr[bufi][((h) * 1024 + 512 + wv * 64) * 8]);   \
    }

    // prologue: B0(0),A0(0),B1(0),A1(0),B0(1),A0(1)
    STG(Bs0, Bs1, ldb, Bh, 0, 0, 0);
    STG(As0, As1, lda, Ah, 0, 0, 0);
    STG(Bs0, Bs1, ldb, Bh, 0, 1, 0);
    STG(As0, As1, lda, Ah, 0, 1, 0);
    STG(Bs0, Bs1, ldb, Bh, 1, 0, 1);
    STG(As0, As1, lda, Ah, 1, 0, 1);

    for (int kt = 0; kt < NT; ++kt) {
        const int cur = kt & 1;
        if (kt + 1 < NT) asm volatile("s_waitcnt vmcnt(4)" ::: "memory");
        else             asm volatile("s_waitcnt vmcnt(0)" ::: "memory");
        SBAR();

        hlf8 a0[4][2], a1[4][2], b0[2][2], b1[2][2];
        // ------ P1: stage B1(kt+1); read a0+b0; MFMA q00 ------
        if (kt + 1 < NT) STG(Bs0, Bs1, ldb, Bh, cur ^ 1, 1, kt + 1);
#pragma unroll
        for (int i = 0; i < 4; ++i)
#pragma unroll
            for (int ks = 0; ks < 2; ++ks) {
                const int rr = wm + i * 16 + fr;
                a0[i][ks] = *(const hlf8*)&Ah[cur][rr * 64 + (((ks * 4 + fq) ^ (rr & 7)) << 3)];
            }
#pragma unroll
        for (int jj = 0; jj < 2; ++jj)
#pragma unroll
            for (int ks = 0; ks < 2; ++ks) {
                const int cc = wn + jj * 16 + fr;
                b0[jj][ks] = *(const hlf8*)&Bh[cur][cc * 64 + (((ks * 4 + fq) ^ (cc & 7)) << 3)];
            }
        SBAR();
        __builtin_amdgcn_s_setprio(1);
#pragma unroll
        for (int i = 0; i < 4; ++i)
#pragma unroll
            for (int jj = 0; jj < 2; ++jj)
#pragma unroll
                for (int ks = 0; ks < 2; ++ks)
                    acc[i][jj] = __builtin_amdgcn_mfma_f32_16x16x32_f16(a0[i][ks], b0[jj][ks], acc[i][jj], 0, 0, 0);
        __builtin_amdgcn_s_setprio(0);
        SBAR();

        // ------ P2: stage A1(kt+1); read b1; MFMA q01 ------
        if (kt + 1 < NT) STG(As0, As1, lda, Ah, cur ^ 1, 1, kt + 1);
#pragma unroll
        for (int jj = 0; jj < 2; ++jj)
#pragma unroll
            for (int ks = 0; ks < 2; ++ks) {
                const int cc = wn + (jj + 2) * 16 + fr;
                b1[jj][ks] = *(const hlf8*)&Bh[cur][cc * 64 + (((ks * 4 + fq) ^ (cc & 7)) << 3)];
            }
        SBAR();
        __builtin_amdgcn_s_setprio(1);
#pragma unroll
        for (int i = 0; i < 4; ++i)
#pragma unroll
            for (int jj = 0; jj < 2; ++jj)
#pragma unroll
                for (int ks = 0; ks < 2; ++ks)
                    acc[i][jj + 2] = __builtin_amdgcn_mfma_f32_16x16x32_f16(a0[i][ks], b1[jj][ks], acc[i][jj + 2], 0, 0, 0);
        __builtin_amdgcn_s_setprio(0);
        SBAR();

        // ------ P3: stage B0(kt+2); read a1; MFMA q10 ------
        if (kt + 2 < NT) STG(Bs0, Bs1, ldb, Bh, cur, 0, kt + 2);
#pragma unroll
        for (int i = 0; i < 4; ++i)
#pragma unroll
            for (int ks = 0; ks < 2; ++ks) {
                const int rr = wm + (i + 4) * 16 + fr;
                a1[i][ks] = *(const hlf8*)&Ah[cur][rr * 64 + (((ks * 4 + fq) ^ (rr & 7)) << 3)];
            }
        SBAR();
        __builtin_amdgcn_s_setprio(1);
#pragma unroll
        for (int i = 0; i < 4; ++i)
#pragma unroll
            for (int jj = 0; jj < 2; ++jj)
#pragma unroll
                for (int ks = 0; ks < 2; ++ks)
                    acc[i + 4][jj] = __builtin_amdgcn_mfma_f32_16x16x32_f16(a1[i][ks], b0[jj][ks], acc[i + 4][jj], 0, 0, 0);
        __builtin_amdgcn_s_setprio(0);
        SBAR();

        // ------ P4: stage A0(kt+2); MFMA q11 (regs only) ------
        if (kt + 2 < NT) STG(As0, As1, lda, Ah, cur, 0, kt + 2);
        __builtin_amdgcn_s_setprio(1);
#pragma unroll
        for (int i = 0; i < 4; ++i)
#pragma unroll
            for (int jj = 0; jj < 2; ++jj)
#pragma unroll
                for (int ks = 0; ks < 2; ++ks)
                    acc[i + 4][jj + 2] = __builtin_amdgcn_mfma_f32_16x16x32_f16(a1[i][ks], b1[jj][ks], acc[i + 4][jj + 2], 0, 0, 0);
        __builtin_amdgcn_s_setprio(0);
    }
#undef STG

    // C/D layout: col=lane&15, row=(lane>>4)*4+reg (m89-verified)
    if constexpr (MODE == 1) {
        _Float16* op = (_Float16*)Cc;
#pragma unroll
        for (int i = 0; i < 8; ++i)
#pragma unroll
            for (int j = 0; j < 4; ++j) {
                _Float16* cp = op + (m0 + wm + i * 16 + fq * 4) * ldc + (n0 + wn + j * 16 + fr);
#pragma unroll
                for (int r = 0; r < 4; ++r)
                    cp[(long long)r * ldc] = (_Float16)__expf(acc[i][j][r] - 5.0f);
            }
    } else {
        float* outp = (gridDim.z == 1) ? (float*)Cc : (part + (long long)bz * zstride);
#pragma unroll
        for (int i = 0; i < 8; ++i)
#pragma unroll
            for (int j = 0; j < 4; ++j) {
                float* cp = outp + (m0 + wm + i * 16 + fq * 4) * ldc + (n0 + wn + j * 16 + fr);
#pragma unroll
                for (int r = 0; r < 4; ++r) cp[(long long)r * ldc] = acc[i][j][r];
            }
    }
}

// ------- split-K reduction with optional per-row scale: out = inv[row]*Σ ----
__global__ __launch_bounds__(256) void k_redux(
    const float* __restrict__ part, float* __restrict__ out,
    long long n4, long long zs4, int Z,
    const float* __restrict__ invs, int rowdiv4) {
    long long i = blockIdx.x * 256ll + threadIdx.x;
    long long stride = (long long)gridDim.x * 256ll;
    for (; i < n4; i += stride) {
        float4 s = ((const float4*)part)[i];
        for (int z = 1; z < Z; ++z) {
            float4 t = ((const float4*)part)[i + z * zs4];
            s.x += t.x; s.y += t.y; s.z += t.z; s.w += t.w;
        }
        if (invs) {
            float iv = invs[i / rowdiv4];
            s.x *= iv; s.y *= iv; s.z *= iv; s.w *= iv;
        }
        ((float4*)out)[i] = s;
    }
}

// ---------------- row LayerNorm in-place (f32), width W = CNT*256 -----------
template <int CNT>
__global__ __launch_bounds__(256) void k_layernorm(
    float* __restrict__ Y, const float* __restrict__ g,
    const float* __restrict__ b, int W) {
    float* yr = Y + (long long)blockIdx.x * W;
    float v[CNT];
    float s = 0.f;
#pragma unroll
    for (int i = 0; i < CNT; ++i) {
        v[i] = yr[threadIdx.x + (i << 8)];
        s += v[i];
    }
    float mu = blk_sum(s) / (float)W;
    float sq = 0.f;
#pragma unroll
    for (int i = 0; i < CNT; ++i) {
        float d = v[i] - mu;
        sq = fmaf(d, d, sq);
    }
    float var = blk_sum(sq) / (float)W;
    float rs = rsqrtf(var + 1e-5f);
#pragma unroll
    for (int i = 0; i < CNT; ++i) {
        int col = threadIdx.x + (i << 8);
        yr[col] = (v[i] - mu) * rs * g[col] + b[col];
    }
}

// ---- row LayerNorm f32 -> f16 (scaled); for q,k whose f32 isn't an output --
__global__ __launch_bounds__(256) void k_layernorm_h(
    const float* __restrict__ Y, const float* __restrict__ g,
    const float* __restrict__ b, _Float16* __restrict__ outh, int W, float sc) {
    const float* yr = Y + (long long)blockIdx.x * W;
    _Float16* orow = outh + (long long)blockIdx.x * W;
    float v = yr[threadIdx.x];                       // W == 256 here
    float mu = blk_sum(v) / (float)W;
    float d = v - mu;
    float var = blk_sum(d * d) / (float)W;
    float rs = rsqrtf(var + 1e-5f);
    orow[threadIdx.x] = (_Float16)((d * rs * g[threadIdx.x] + b[threadIdx.x]) * sc);
}

// -------- sum-only softmax over E = exp(S-5) f16, W = 16384 -----------------
__global__ __launch_bounds__(256) void k_softmax_e(
    const _Float16* __restrict__ E, float* __restrict__ attnf,
    float* __restrict__ invs) {
    const _Float16* er = E + (long long)blockIdx.x * 16384;
    float* ar = attnf + (long long)blockIdx.x * 16384;
    float4 r[16];
    float sum = 0.f;
#pragma unroll
    for (int i = 0; i < 16; ++i) {
        hlf4 h = ((const hlf4*)er)[threadIdx.x + (i << 8)];
        float4 t = {(float)h[0], (float)h[1], (float)h[2], (float)h[3]};
        r[i] = t;
        sum += t.x + t.y + t.z + t.w;
    }
    sum = blk_sum(sum);
    float inv = 1.0f / sum;
    if (threadIdx.x == 0) invs[blockIdx.x] = inv;
#pragma unroll
    for (int i = 0; i < 16; ++i) {
        float4 t = r[i];
        t.x *= inv; t.y *= inv; t.z *= inv; t.w *= inv;
        ((float4*)ar)[threadIdx.x + (i << 8)] = t;
    }
}

extern "C" void kernel_launch(void* const* d_in, const int* in_sizes, int n_in,
                              void* d_out, int out_size, void* d_ws, size_t ws_size,
                              hipStream_t stream) {
    const float* x      = (const float*)d_in[0];
    const float* X_data = (const float*)d_in[1];
    const int*   midx   = (const int*)d_in[2];
    const float* W_q    = (const float*)d_in[3];
    const float* W_k    = (const float*)d_in[4];
    const float* W_v    = (const float*)d_in[5];
    const float* g_q    = (const float*)d_in[6];
    const float* b_q    = (const float*)d_in[7];
    const float* g_k    = (const float*)d_in[8];
    const float* b_k    = (const float*)d_in[9];
    const float* g_v    = (const float*)d_in[10];
    const float* b_v    = (const float*)d_in[11];

    const int n  = in_sizes[10];        // 1024
    const int a  = in_sizes[6];         // 256
    const int m  = in_sizes[2];         // 16384
    const int Bn = in_sizes[0] / n;     // 4096

    // output layout: xs | x_hat | attn | v
    float* out  = (float*)d_out;
    float* xs   = out;
    float* xhat = xs + (long long)Bn * n;
    float* attn = xhat + (long long)Bn * n;
    float* vout = attn + (long long)Bn * m;

    char* wp = (char*)d_ws;
    auto carve = [&](size_t bytes) -> char* {
        char* r = wp; wp += (bytes + 255) & ~(size_t)255; return r;
    };
    float*     norms = (float*)carve((size_t)m * 4);
    float*     cinv  = (float*)carve(16);
    float*     invs  = (float*)carve((size_t)Bn * 4);
    char*      alias0 = wp;
    float*     qmat  = (float*)carve((size_t)Bn * a * 4);
    float*     kmat  = (float*)carve((size_t)m * a * 4);
    _Float16*  xs_h  = (_Float16*)carve((size_t)Bn * n * 2);
    _Float16*  Xc_h  = (_Float16*)carve((size_t)m * n * 2);
    _Float16*  Wq_h  = (_Float16*)carve((size_t)a * n * 2);
    _Float16*  Wk_h  = (_Float16*)carve((size_t)a * n * 2);
    _Float16*  Wv_h  = (_Float16*)carve((size_t)n * n * 2);
    _Float16*  q_h   = (_Float16*)carve((size_t)Bn * a * 2);
    _Float16*  k_h   = (_Float16*)carve((size_t)m * a * 2);
    float*     splitk = (float*)alias0;
    const int  SK = 4;                                    // SK*Bn*n*4 = 64MB <= 73MB
    _Float16*  vT_h  = (_Float16*)carve((size_t)n * m * 2);
    size_t used = (size_t)(wp - (char*)d_ws);
    _Float16* attn_h = nullptr;
    if (ws_size >= used + (size_t)Bn * m * 2 + 256)
        attn_h = (_Float16*)carve((size_t)Bn * m * 2);

    // 1) gather + cvt + fused row norms; then 1/C
    hipLaunchKernelGGL(k_gather_cvt, dim3(m), dim3(256), 0, stream,
                       X_data, midx, Xc_h, norms, n);
    hipLaunchKernelGGL(k_cinv, dim3(1), dim3(256), 0, stream, norms, m, n, cinv);

    // 2) xs = x/C (f32 output) + unscaled f16 copy for q projection
    hipLaunchKernelGGL(k_scale2, dim3(2048), dim3(256), 0, stream,
                       x, cinv, xs, xs_h, (long long)Bn * n / 4);

    // 3) weights -> f16
    hipLaunchKernelGGL(k_cvt, dim3(256), dim3(256), 0, stream, W_q, Wq_h, (long long)a * n / 4, 1.f);
    hipLaunchKernelGGL(k_cvt, dim3(256), dim3(256), 0, stream, W_k, Wk_h, (long long)a * n / 4, 1.f);
    hipLaunchKernelGGL(k_cvt, dim3(1024), dim3(256), 0, stream, W_v, Wv_h, (long long)n * n / 4, 1.f);

    // 4) projections: q,k on 128²; v on the 8-phase 256² kernel
    hipLaunchKernelGGL(k_gemm4, dim3(Bn / 128, a / 128), dim3(256), 0, stream,
                       xs_h, n, Wq_h, n, qmat, a, n);
    hipLaunchKernelGGL(k_gemm4, dim3(m / 128, a / 128), dim3(256), 0, stream,
                       Xc_h, n, Wk_h, n, kmat, a, n);
    hipLaunchKernelGGL((k256<0>), dim3(m / 256, n / 256), dim3(512), 0, stream,
                       Xc_h, n, Wv_h, n, vout, n, n, (float*)nullptr, 0ll);

    // 5) LayerNorms: q,k fused f32->f16 (scale folded); v f32 + transposed f16
    float sc = 1.0f / sqrtf((float)a);
    hipLaunchKernelGGL(k_layernorm_h, dim3(Bn), dim3(256), 0, stream,
                       qmat, g_q, b_q, q_h, a, sc);
    hipLaunchKernelGGL(k_layernorm_h, dim3(m), dim3(256), 0, stream,
                       kmat, g_k, b_k, k_h, a, 1.f);
    hipLaunchKernelGGL(k_layernorm<4>, dim3(m), dim3(256), 0, stream, vout, g_v, b_v, n);
    hipLaunchKernelGGL(k_tcvt, dim3(n / 32, m / 32), dim3(256), 0, stream, vout, vT_h, m, n);

    long long zstride = (long long)Bn * n;
    if (attn_h) {
        // 6) E = exp(q·kᵀ·sc − 5) f16 in 256²-GEMM epilogue; sum-only softmax
        hipLaunchKernelGGL((k256<1>), dim3(Bn / 256, m / 256), dim3(512), 0, stream,
                           q_h, a, k_h, a, attn_h, m, a, (float*)nullptr, 0ll);
        hipLaunchKernelGGL(k_softmax_e, dim3(Bn), dim3(256), 0, stream,
                           attn_h, attn, invs);
        // 7) x_hat = (E @ v) * inv_sum[row], split-K=4 + scaled reduce
        hipLaunchKernelGGL((k256<0>), dim3(Bn / 256, n / 256, SK), dim3(512), 0, stream,
                           attn_h, m, vT_h, m, xhat, n, m, splitk, zstride);
        hipLaunchKernelGGL(k_redux, dim3(2048), dim3(256), 0, stream,
                           splitk, xhat, (long long)Bn * n / 4, zstride / 4, SK,
                           invs, n / 4);
    } else {
        // fallback (never exercised): chunked E in splitk region
        _Float16* chunk_h = (_Float16*)splitk;           // 1024*16384*2 = 32MB
        for (int cb = 0; cb < 4; ++cb) {
            hipLaunchKernelGGL((k256<1>), dim3(1024 / 256, m / 256), dim3(512), 0, stream,
                               q_h + (long long)cb * 1024 * a, a, k_h, a,
                               chunk_h, m, a, (float*)nullptr, 0ll);
            hipLaunchKernelGGL(k_softmax_e, dim3(1024), dim3(256), 0, stream,
                               chunk_h, attn + (long long)cb * 1024 * m,
                               invs + (long long)cb * 1024);
            hipLaunchKernelGGL((k256<0>), dim3(1024 / 256, n / 256), dim3(512), 0, stream,
                               chunk_h, m, vT_h, m, xhat + (long long)cb * 1024 * n, n, m,
                               (float*)nullptr, 0ll);
        }
        hipLaunchKernelGGL(k_redux, dim3(2048), dim3(256), 0, stream,
                           xhat, xhat, (long long)Bn * n / 4, 0ll, 1, invs, n / 4);
    }
}

// Round 15
// 544.773 us; speedup vs baseline: 1.0309x; 1.0276x over previous
//
#include <hip/hip_runtime.h>
#include <math.h>

typedef _Float16 hlf4 __attribute__((ext_vector_type(4)));
typedef _Float16 hlf8 __attribute__((ext_vector_type(8)));
typedef float f32x4 __attribute__((ext_vector_type(4)));

// async global->LDS, 16B per lane; lds base must be wave-uniform
static __device__ __forceinline__ void gl_lds16(const void* g, void* l) {
    __builtin_amdgcn_global_load_lds(
        (const __attribute__((address_space(1))) unsigned int*)g,
        (__attribute__((address_space(3))) unsigned int*)l, 16, 0, 0);
}

// ---------------- block reductions (deterministic tree order) ----------------
static __device__ __forceinline__ float blk_sum(float v) {
    __shared__ float sm[256];
    int tid = threadIdx.x;
    sm[tid] = v; __syncthreads();
#pragma unroll
    for (int s = 128; s > 0; s >>= 1) {
        if (tid < s) sm[tid] += sm[tid + s];
        __syncthreads();
    }
    float r = sm[0]; __syncthreads();
    return r;
}

__global__ __launch_bounds__(256) void k_cinv(
    const float* __restrict__ norms, int m, int n, float* __restrict__ cinv) {
    float s = 0.f;
    for (int i = threadIdx.x; i < m; i += 256) s += norms[i];
    float tot = blk_sum(s);
    if (threadIdx.x == 0) cinv[0] = (float)m * sqrtf((float)n) / tot;  // 1/C
}

// ------- xs = x * (1/C) f32 (output) + UNSCALED f16 copy (LN-invariant) -----
__global__ __launch_bounds__(256) void k_scale2(
    const float* __restrict__ x, const float* __restrict__ cinv,
    float* __restrict__ y, _Float16* __restrict__ yh, long long total4) {
    float c = cinv[0];
    long long i = blockIdx.x * 256ll + threadIdx.x;
    long long stride = (long long)gridDim.x * 256ll;
    for (; i < total4; i += stride) {
        float4 v = ((const float4*)x)[i];
        float4 w = {v.x * c, v.y * c, v.z * c, v.w * c};
        ((float4*)y)[i] = w;
        hlf4 o = {(_Float16)v.x, (_Float16)v.y, (_Float16)v.z, (_Float16)v.w};
        ((hlf4*)yh)[i] = o;
    }
}

// ---- gather + cvt + fused row-norm (row already in registers) ----
__global__ __launch_bounds__(256) void k_gather_cvt(
    const float* __restrict__ X, const int* __restrict__ idx,
    _Float16* __restrict__ out, float* __restrict__ norms, int n) {
    long long r = idx[blockIdx.x];
    const float* src = X + r * (long long)n;
    _Float16* dst = out + (long long)blockIdx.x * n;
    float s = 0.f;
    for (int k = threadIdx.x * 4; k < n; k += 256 * 4) {
        float4 v = *(const float4*)(src + k);
        hlf4 o = {(_Float16)v.x, (_Float16)v.y, (_Float16)v.z, (_Float16)v.w};
        *(hlf4*)(dst + k) = o;
        s = fmaf(v.x, v.x, s); s = fmaf(v.y, v.y, s);
        s = fmaf(v.z, v.z, s); s = fmaf(v.w, v.w, s);
    }
    float tot = blk_sum(s);
    if (threadIdx.x == 0) norms[blockIdx.x] = sqrtf(tot);
}

// --------- merged f32->f16 cvt for the three weight matrices (1 launch) -----
__global__ __launch_bounds__(256) void k_cvt3(
    const float* __restrict__ s0, _Float16* __restrict__ d0, long long c0,
    const float* __restrict__ s1, _Float16* __restrict__ d1, long long c1,
    const float* __restrict__ s2, _Float16* __restrict__ d2, long long c2) {
    long long total = c0 + c1 + c2;
    long long i = blockIdx.x * 256ll + threadIdx.x;
    long long stride = (long long)gridDim.x * 256ll;
    for (; i < total; i += stride) {
        const float* s; _Float16* d; long long j = i;
        if (j < c0) { s = s0; d = d0; }
        else if (j - c0 < c1) { j -= c0; s = s1; d = d1; }
        else { j -= c0 + c1; s = s2; d = d2; }
        float4 v = ((const float4*)s)[j];
        hlf4 o = {(_Float16)v.x, (_Float16)v.y, (_Float16)v.z, (_Float16)v.w};
        ((hlf4*)d)[j] = o;
    }
}

// ---------------- transpose + cvt: in[R][Cc] f32 -> out[Cc][R] f16 ----------
__global__ __launch_bounds__(256) void k_tcvt(
    const float* __restrict__ in, _Float16* __restrict__ out, int R, int Cc) {
    __shared__ _Float16 t[32][34];
    int tx = threadIdx.x & 31, ty = threadIdx.x >> 5;
    int c0 = blockIdx.x * 32, r0 = blockIdx.y * 32;
#pragma unroll
    for (int i = 0; i < 32; i += 8)
        t[ty + i][tx] = (_Float16)in[(long long)(r0 + ty + i) * Cc + c0 + tx];
    __syncthreads();
#pragma unroll
    for (int i = 0; i < 32; i += 8)
        out[(long long)(c0 + ty + i) * R + r0 + tx] = t[tx][ty + i];
}

// ================= m97-structure MFMA NT GEMM (128² tile, 4 waves) ==========
// Proven kernel (R12 config = fastest measured). XCD bijective remap then
// BY-FASTEST decomposition (A-panel-sharing blocks consecutive on one XCD).
// MODE: 0 = f32 C (direct or split-K partial); 1 = f16 exp(C-5) epilogue
// (fixed-shift softmax: |S|<=16 by Cauchy-Schwarz on LN rows * 1/sqrt(a)).
template <int MODE>
__global__ __launch_bounds__(256) void k_gemm4(
    const _Float16* __restrict__ A, int lda,
    const _Float16* __restrict__ B, int ldb,
    void* __restrict__ Cc, long long ldc, int K,
    float* __restrict__ part, long long zstride) {
    __shared__ _Float16 Ah[2][4096];
    __shared__ _Float16 Bh[2][4096];
    const int tid = threadIdx.x;

    const int gx = gridDim.x, gy = gridDim.y;
    int lin = blockIdx.x + gx * (blockIdx.y + gy * blockIdx.z);
    const int cpx = (gx * gy * (int)gridDim.z) >> 3;   // nwg always %8==0
    lin = (lin & 7) * cpx + (lin >> 3);                // XCD-contiguous chunks
    const int by = lin % gy;                           // N fastest: A reuse
    const int rest = lin / gy;
    const int bx = rest % gx, bz = rest / gx;

    const long long m0 = (long long)bx * 128;
    const long long n0 = (long long)by * 128;
    const int KC = K / gridDim.z;
    const int kbase = bz * KC;
    const int lane = tid & 63, wv = tid >> 6;
    const int wm = (wv >> 1) * 64, wn = (wv & 1) * 64;
    const int fr = lane & 15, fq = lane >> 4;

    const int s0 = tid, s1 = tid + 256;
    const int r0s = s0 >> 2, r1s = s1 >> 2;
    const int g0 = (((s0 & 3) ^ (r0s & 3)) << 3);
    const int g1 = (((s1 & 3) ^ (r1s & 3)) << 3);
    const _Float16* A0 = A + (m0 + r0s) * (long long)lda + kbase + g0;
    const _Float16* A1 = A + (m0 + r1s) * (long long)lda + kbase + g1;
    const _Float16* B0 = B + (n0 + r0s) * (long long)ldb + kbase + g0;
    const _Float16* B1 = B + (n0 + r1s) * (long long)ldb + kbase + g1;

    f32x4 acc[4][4] = {};

    const int NT = KC / 32;
    {
        gl_lds16(A0, &Ah[0][wv * 512]);
        gl_lds16(A1, &Ah[0][2048 + wv * 512]);
        gl_lds16(B0, &Bh[0][wv * 512]);
        gl_lds16(B1, &Bh[0][2048 + wv * 512]);
    }
    __syncthreads();

    for (int kt = 0; kt < NT; ++kt) {
        const int cur = kt & 1;
        if (kt + 1 < NT) {
            const int nx = cur ^ 1;
            const long long ko = (long long)(kt + 1) * 32;
            gl_lds16(A0 + ko, &Ah[nx][wv * 512]);
            gl_lds16(A1 + ko, &Ah[nx][2048 + wv * 512]);
            gl_lds16(B0 + ko, &Bh[nx][wv * 512]);
            gl_lds16(B1 + ko, &Bh[nx][2048 + wv * 512]);
        }
        hlf8 af[4], bf[4];
#pragma unroll
        for (int i = 0; i < 4; ++i) {
            const int r = wm + i * 16 + fr;
            af[i] = *(const hlf8*)&Ah[cur][r * 32 + ((fq ^ (r & 3)) << 3)];
        }
#pragma unroll
        for (int j = 0; j < 4; ++j) {
            const int r = wn + j * 16 + fr;
            bf[j] = *(const hlf8*)&Bh[cur][r * 32 + ((fq ^ (r & 3)) << 3)];
        }
#pragma unroll
        for (int i = 0; i < 4; ++i)
#pragma unroll
            for (int j = 0; j < 4; ++j)
                acc[i][j] = __builtin_amdgcn_mfma_f32_16x16x32_f16(af[i], bf[j], acc[i][j], 0, 0, 0);
        __syncthreads();
    }

    // C/D layout: col=lane&15, row=(lane>>4)*4+reg (m89-verified)
    if constexpr (MODE == 1) {
        _Float16* op = (_Float16*)Cc;
#pragma unroll
        for (int i = 0; i < 4; ++i)
#pragma unroll
            for (int j = 0; j < 4; ++j) {
                _Float16* cp = op + (m0 + wm + i * 16 + fq * 4) * ldc + (n0 + wn + j * 16 + fr);
#pragma unroll
                for (int r = 0; r < 4; ++r)
                    cp[(long long)r * ldc] = (_Float16)__expf(acc[i][j][r] - 5.0f);
            }
    } else {
        float* outp = (gridDim.z == 1) ? (float*)Cc : (part + (long long)bz * zstride);
#pragma unroll
        for (int i = 0; i < 4; ++i)
#pragma unroll
            for (int j = 0; j < 4; ++j) {
                float* cp = outp + (m0 + wm + i * 16 + fq * 4) * ldc + (n0 + wn + j * 16 + fr);
#pragma unroll
                for (int r = 0; r < 4; ++r) cp[(long long)r * ldc] = acc[i][j][r];
            }
    }
}

// ------- split-K reduction with optional per-row scale: out = inv[row]*Σ ----
__global__ __launch_bounds__(256) void k_redux(
    const float* __restrict__ part, float* __restrict__ out,
    long long n4, long long zs4, int Z,
    const float* __restrict__ invs, int rowdiv4) {
    long long i = blockIdx.x * 256ll + threadIdx.x;
    long long stride = (long long)gridDim.x * 256ll;
    for (; i < n4; i += stride) {
        float4 s = ((const float4*)part)[i];
        for (int z = 1; z < Z; ++z) {
            float4 t = ((const float4*)part)[i + z * zs4];
            s.x += t.x; s.y += t.y; s.z += t.z; s.w += t.w;
        }
        if (invs) {
            float iv = invs[i / rowdiv4];
            s.x *= iv; s.y *= iv; s.z *= iv; s.w *= iv;
        }
        ((float4*)out)[i] = s;
    }
}

// ---------------- row LayerNorm in-place (f32), width W = CNT*256 -----------
template <int CNT>
__global__ __launch_bounds__(256) void k_layernorm(
    float* __restrict__ Y, const float* __restrict__ g,
    const float* __restrict__ b, int W) {
    float* yr = Y + (long long)blockIdx.x * W;
    float v[CNT];
    float s = 0.f;
#pragma unroll
    for (int i = 0; i < CNT; ++i) {
        v[i] = yr[threadIdx.x + (i << 8)];
        s += v[i];
    }
    float mu = blk_sum(s) / (float)W;
    float sq = 0.f;
#pragma unroll
    for (int i = 0; i < CNT; ++i) {
        float d = v[i] - mu;
        sq = fmaf(d, d, sq);
    }
    float var = blk_sum(sq) / (float)W;
    float rs = rsqrtf(var + 1e-5f);
#pragma unroll
    for (int i = 0; i < CNT; ++i) {
        int col = threadIdx.x + (i << 8);
        yr[col] = (v[i] - mu) * rs * g[col] + b[col];
    }
}

// ---- merged q+k row LayerNorm f32 -> f16 (scale folded), W = 256 -----------
// grid = nq + nk rows; row < nq -> q stream (scale sc), else k stream.
__global__ __launch_bounds__(256) void k_lnh2(
    const float* __restrict__ Yq, const float* __restrict__ gq,
    const float* __restrict__ bq, _Float16* __restrict__ oq, float scq, int nq,
    const float* __restrict__ Yk, const float* __restrict__ gk,
    const float* __restrict__ bk, _Float16* __restrict__ ok) {
    const int row = blockIdx.x;
    const float* yr; const float* g; const float* b; _Float16* o; float sc;
    if (row < nq) {
        yr = Yq + (long long)row * 256; g = gq; b = bq;
        o = oq + (long long)row * 256; sc = scq;
    } else {
        const int r = row - nq;
        yr = Yk + (long long)r * 256; g = gk; b = bk;
        o = ok + (long long)r * 256; sc = 1.f;
    }
    float v = yr[threadIdx.x];
    float mu = blk_sum(v) / 256.f;
    float d = v - mu;
    float var = blk_sum(d * d) / 256.f;
    float rs = rsqrtf(var + 1e-5f);
    o[threadIdx.x] = (_Float16)((d * rs * g[threadIdx.x] + b[threadIdx.x]) * sc);
}

// -------- sum-only softmax over E = exp(S-5) f16, W = 16384 -----------------
// writes attn = E*inv (f32) and invs[row] = 1/sum for the x_hat epilogue.
__global__ __launch_bounds__(256) void k_softmax_e(
    const _Float16* __restrict__ E, float* __restrict__ attnf,
    float* __restrict__ invs) {
    const _Float16* er = E + (long long)blockIdx.x * 16384;
    float* ar = attnf + (long long)blockIdx.x * 16384;
    float4 r[16];
    float sum = 0.f;
#pragma unroll
    for (int i = 0; i < 16; ++i) {
        hlf4 h = ((const hlf4*)er)[threadIdx.x + (i << 8)];
        float4 t = {(float)h[0], (float)h[1], (float)h[2], (float)h[3]};
        r[i] = t;
        sum += t.x + t.y + t.z + t.w;
    }
    sum = blk_sum(sum);
    float inv = 1.0f / sum;
    if (threadIdx.x == 0) invs[blockIdx.x] = inv;
#pragma unroll
    for (int i = 0; i < 16; ++i) {
        float4 t = r[i];
        t.x *= inv; t.y *= inv; t.z *= inv; t.w *= inv;
        ((float4*)ar)[threadIdx.x + (i << 8)] = t;
    }
}

extern "C" void kernel_launch(void* const* d_in, const int* in_sizes, int n_in,
                              void* d_out, int out_size, void* d_ws, size_t ws_size,
                              hipStream_t stream) {
    const float* x      = (const float*)d_in[0];
    const float* X_data = (const float*)d_in[1];
    const int*   midx   = (const int*)d_in[2];
    const float* W_q    = (const float*)d_in[3];
    const float* W_k    = (const float*)d_in[4];
    const float* W_v    = (const float*)d_in[5];
    const float* g_q    = (const float*)d_in[6];
    const float* b_q    = (const float*)d_in[7];
    const float* g_k    = (const float*)d_in[8];
    const float* b_k    = (const float*)d_in[9];
    const float* g_v    = (const float*)d_in[10];
    const float* b_v    = (const float*)d_in[11];

    const int n  = in_sizes[10];        // 1024
    const int a  = in_sizes[6];         // 256
    const int m  = in_sizes[2];         // 16384
    const int Bn = in_sizes[0] / n;     // 4096

    // output layout: xs | x_hat | attn | v
    float* out  = (float*)d_out;
    float* xs   = out;
    float* xhat = xs + (long long)Bn * n;
    float* attn = xhat + (long long)Bn * n;
    float* vout = attn + (long long)Bn * m;

    // workspace carving (256B aligned). [qmat .. k_h] (~73 MB) is dead before
    // the x_hat GEMM, so the 64 MB split-K partial buffer aliases it.
    // invs lives OUTSIDE the aliased span (read after partials written).
    char* wp = (char*)d_ws;
    auto carve = [&](size_t bytes) -> char* {
        char* r = wp; wp += (bytes + 255) & ~(size_t)255; return r;
    };
    float*     norms = (float*)carve((size_t)m * 4);
    float*     cinv  = (float*)carve(16);
    float*     invs  = (float*)carve((size_t)Bn * 4);
    char*      alias0 = wp;
    float*     qmat  = (float*)carve((size_t)Bn * a * 4);
    float*     kmat  = (float*)carve((size_t)m * a * 4);
    _Float16*  xs_h  = (_Float16*)carve((size_t)Bn * n * 2);
    _Float16*  Xc_h  = (_Float16*)carve((size_t)m * n * 2);
    _Float16*  Wq_h  = (_Float16*)carve((size_t)a * n * 2);
    _Float16*  Wk_h  = (_Float16*)carve((size_t)a * n * 2);
    _Float16*  Wv_h  = (_Float16*)carve((size_t)n * n * 2);
    _Float16*  q_h   = (_Float16*)carve((size_t)Bn * a * 2);
    _Float16*  k_h   = (_Float16*)carve((size_t)m * a * 2);
    float*     splitk = (float*)alias0;
    const int  SK = 4;                                    // SK*Bn*n*4 = 64MB <= 73MB
    _Float16*  vT_h  = (_Float16*)carve((size_t)n * m * 2);
    size_t used = (size_t)(wp - (char*)d_ws);
    _Float16* attn_h = nullptr;
    if (ws_size >= used + (size_t)Bn * m * 2 + 256)
        attn_h = (_Float16*)carve((size_t)Bn * m * 2);

    // 1) gather + cvt + fused row norms; then 1/C
    hipLaunchKernelGGL(k_gather_cvt, dim3(m), dim3(256), 0, stream,
                       X_data, midx, Xc_h, norms, n);
    hipLaunchKernelGGL(k_cinv, dim3(1), dim3(256), 0, stream, norms, m, n, cinv);

    // 2) xs = x/C (f32 output) + unscaled f16 copy for q projection
    hipLaunchKernelGGL(k_scale2, dim3(2048), dim3(256), 0, stream,
                       x, cinv, xs, xs_h, (long long)Bn * n / 4);

    // 3) all three weights -> f16 in ONE launch
    hipLaunchKernelGGL(k_cvt3, dim3(1536), dim3(256), 0, stream,
                       W_q, Wq_h, (long long)a * n / 4,
                       W_k, Wk_h, (long long)a * n / 4,
                       W_v, Wv_h, (long long)n * n / 4);

    // 4) projections (all on proven 128² kernel, A-reuse block ordering)
    hipLaunchKernelGGL((k_gemm4<0>), dim3(Bn / 128, a / 128), dim3(256), 0, stream,
                       xs_h, n, Wq_h, n, qmat, a, n, (float*)nullptr, 0ll);
    hipLaunchKernelGGL((k_gemm4<0>), dim3(m / 128, a / 128), dim3(256), 0, stream,
                       Xc_h, n, Wk_h, n, kmat, a, n, (float*)nullptr, 0ll);
    hipLaunchKernelGGL((k_gemm4<0>), dim3(m / 128, n / 128), dim3(256), 0, stream,
                       Xc_h, n, Wv_h, n, vout, n, n, (float*)nullptr, 0ll);

    // 5) LayerNorms: q+k fused f32->f16 in ONE launch (scale folded);
    //    v in-place f32 (required output) + transposed f16 copy
    float sc = 1.0f / sqrtf((float)a);
    hipLaunchKernelGGL(k_lnh2, dim3(Bn + m), dim3(256), 0, stream,
                       qmat, g_q, b_q, q_h, sc, Bn,
                       kmat, g_k, b_k, k_h);
    hipLaunchKernelGGL(k_layernorm<4>, dim3(m), dim3(256), 0, stream, vout, g_v, b_v, n);
    hipLaunchKernelGGL(k_tcvt, dim3(n / 32, m / 32), dim3(256), 0, stream, vout, vT_h, m, n);

    long long zstride = (long long)Bn * n;
    if (attn_h) {
        // 6) E = exp(q·kᵀ·sc − 5) f16 in GEMM epilogue; sum-only softmax
        hipLaunchKernelGGL((k_gemm4<1>), dim3(Bn / 128, m / 128), dim3(256), 0, stream,
                           q_h, a, k_h, a, attn_h, m, a, (float*)nullptr, 0ll);
        hipLaunchKernelGGL(k_softmax_e, dim3(Bn), dim3(256), 0, stream,
                           attn_h, attn, invs);
        // 7) x_hat = (E @ v) * inv_sum[row], split-K=4 + scaled reduce
        hipLaunchKernelGGL((k_gemm4<0>), dim3(Bn / 128, n / 128, SK), dim3(256), 0, stream,
                           attn_h, m, vT_h, m, xhat, n, m, splitk, zstride);
        hipLaunchKernelGGL(k_redux, dim3(2048), dim3(256), 0, stream,
                           splitk, xhat, (long long)Bn * n / 4, zstride / 4, SK,
                           invs, n / 4);
    } else {
        // fallback (never exercised; ws has always fit): chunked E in splitk
        _Float16* chunk_h = (_Float16*)splitk;           // 1024*16384*2 = 32MB
        for (int cb = 0; cb < 4; ++cb) {
            hipLaunchKernelGGL((k_gemm4<1>), dim3(1024 / 128, m / 128), dim3(256), 0, stream,
                               q_h + (long long)cb * 1024 * a, a, k_h, a,
                               chunk_h, m, a, (float*)nullptr, 0ll);
            hipLaunchKernelGGL(k_softmax_e, dim3(1024), dim3(256), 0, stream,
                               chunk_h, attn + (long long)cb * 1024 * m,
                               invs + (long long)cb * 1024);
            hipLaunchKernelGGL((k_gemm4<0>), dim3(1024 / 128, n / 128), dim3(256), 0, stream,
                               chunk_h, m, vT_h, m, xhat + (long long)cb * 1024 * n, n, m,
                               (float*)nullptr, 0ll);
        }
        hipLaunchKernelGGL(k_redux, dim3(2048), dim3(256), 0, stream,
                           xhat, xhat, (long long)Bn * n / 4, 0ll, 1, invs, n / 4);
    }
}